// Round 4
// 325.692 us; speedup vs baseline: 1.0002x; 1.0002x over previous
//
#include <hip/hip_runtime.h>

typedef float f32x4 __attribute__((ext_vector_type(4)));
typedef int   i32x4 __attribute__((ext_vector_type(4)));
typedef int   i32x8 __attribute__((ext_vector_type(8)));

#define FP8MAX 448.0f
#define AMAX_BLOCKS 2048
#define WQ_BLOCKS 512
#define QA_BLOCKS 2048

// ---------------- fused: amax partials (blocks 0..2047) + weight quant (blocks 2048..2559) ----------------

__device__ __forceinline__ unsigned pack_fp8_exact(float4 v) {
    int r = __builtin_amdgcn_cvt_pk_fp8_f32(v.x, v.y, 0, false);
    return (unsigned)__builtin_amdgcn_cvt_pk_fp8_f32(v.z, v.w, r, true);
}

__global__ __launch_bounds__(256) void amax_and_wquant(
    const float4* __restrict__ x, float* __restrict__ partial, int n4,
    const float4* __restrict__ w, uint4* __restrict__ qw, int n16w) {
    if (blockIdx.x < AMAX_BLOCKS) {
        // grid-stride abs-max over the activation, two accumulators to break the chain
        float m0 = 0.0f, m1 = 0.0f;
        int stride = AMAX_BLOCKS * 256;
        int i = blockIdx.x * 256 + threadIdx.x;
        for (; i + stride < n4; i += 2 * stride) {
            float4 a = x[i];
            float4 b = x[i + stride];
            m0 = fmaxf(m0, fmaxf(fmaxf(fabsf(a.x), fabsf(a.y)), fmaxf(fabsf(a.z), fabsf(a.w))));
            m1 = fmaxf(m1, fmaxf(fmaxf(fabsf(b.x), fabsf(b.y)), fmaxf(fabsf(b.z), fabsf(b.w))));
        }
        if (i < n4) {
            float4 a = x[i];
            m0 = fmaxf(m0, fmaxf(fmaxf(fabsf(a.x), fabsf(a.y)), fmaxf(fabsf(a.z), fabsf(a.w))));
        }
        float m = fmaxf(m0, m1);
#pragma unroll
        for (int off = 32; off > 0; off >>= 1)
            m = fmaxf(m, __shfl_down(m, off, 64));
        __shared__ float ws[4];
        if ((threadIdx.x & 63) == 0) ws[threadIdx.x >> 6] = m;
        __syncthreads();
        if (threadIdx.x == 0)
            partial[blockIdx.x] = fmaxf(fmaxf(ws[0], ws[1]), fmaxf(ws[2], ws[3]));
    } else {
        // weight quantization: values already on the fp8 grid -> conversion exact
        int stride = WQ_BLOCKS * 256;
        for (int i = (blockIdx.x - AMAX_BLOCKS) * 256 + threadIdx.x; i < n16w; i += stride) {
            uint4 r;
            r.x = pack_fp8_exact(w[i * 4 + 0]);
            r.y = pack_fp8_exact(w[i * 4 + 1]);
            r.z = pack_fp8_exact(w[i * 4 + 2]);
            r.w = pack_fp8_exact(w[i * 4 + 3]);
            qw[i] = r;
        }
    }
}

// ---------------- act quant; every block self-reduces the partials (no extra kernel) ----------------

__device__ __forceinline__ float reduce_partials(const float* __restrict__ partial) {
    // all blocks compute the identical max over AMAX_BLOCKS entries (L2-warm)
    float m = 0.0f;
#pragma unroll
    for (int j = 0; j < AMAX_BLOCKS / 256; ++j)
        m = fmaxf(m, partial[threadIdx.x + j * 256]);
#pragma unroll
    for (int off = 32; off > 0; off >>= 1)
        m = fmaxf(m, __shfl_down(m, off, 64));
    __shared__ float ws[4];
    if ((threadIdx.x & 63) == 0) ws[threadIdx.x >> 6] = m;
    __syncthreads();
    return fmaxf(fmaxf(ws[0], ws[1]), fmaxf(ws[2], ws[3]));
}

__device__ __forceinline__ unsigned pack_fp8_clip(float4 v, float s) {
    float a = fminf(fmaxf(v.x * s, -FP8MAX), FP8MAX);
    float b = fminf(fmaxf(v.y * s, -FP8MAX), FP8MAX);
    float c = fminf(fmaxf(v.z * s, -FP8MAX), FP8MAX);
    float d = fminf(fmaxf(v.w * s, -FP8MAX), FP8MAX);
    int r = __builtin_amdgcn_cvt_pk_fp8_f32(a, b, 0, false);
    r = __builtin_amdgcn_cvt_pk_fp8_f32(c, d, r, true);
    return (unsigned)r;
}

__global__ __launch_bounds__(256) void quant_act(
    const float4* __restrict__ x, uint4* __restrict__ q,
    const float* __restrict__ partial, unsigned* __restrict__ amax_bits, int n16) {
    float amax = fmaxf(reduce_partials(partial), 1e-12f);
    if (blockIdx.x == 0 && threadIdx.x == 0)
        *amax_bits = __float_as_uint(amax);          // publish for the GEMM epilogue
    float s = FP8MAX / amax;                          // same fp32 op order as reference
    int stride = QA_BLOCKS * 256;
    for (int i = blockIdx.x * 256 + threadIdx.x; i < n16; i += stride) {
        uint4 r;
        r.x = pack_fp8_clip(x[i * 4 + 0], s);
        r.y = pack_fp8_clip(x[i * 4 + 1], s);
        r.z = pack_fp8_clip(x[i * 4 + 2], s);
        r.w = pack_fp8_clip(x[i * 4 + 3], s);
        q[i] = r;
    }
}

// ---------------- MX-fp8 GEMM, C = A(MxK) * B(NxK)^T ----------------
// 128x128 tile, BK=128 bytes, 4 waves (2x2), each wave 4x4 accs of
// 16x16x128 mfma_scale (scales = e8m0 127 = x1.0, numerically identical to
// plain fp8 MFMA). LDS rows are 128 B (8 x 16B chunks); logical chunk c of
// row r sits at position c ^ (r&7) -- permutation applied on the GLOBAL
// source side so the global_load_lds destination stays lane-contiguous.

__global__ __launch_bounds__(256) void gemm_fp8_mx(
    const unsigned char* __restrict__ Aq,   // [M,K] fp8
    const unsigned char* __restrict__ Bq,   // [N,K] fp8
    const unsigned* __restrict__ amax_bits,
    const float* __restrict__ w_scale_p,
    const float* __restrict__ bias,
    float* __restrict__ C,
    int M, int N, int K) {
    __shared__ unsigned char lA[128 * 128];
    __shared__ unsigned char lB[128 * 128];

    const int tid = threadIdx.x;
    const int lane = tid & 63;
    const int wave = tid >> 6;

    const int bn = blockIdx.x;   // N fastest: A-tile reuse across bn in L2
    const int bm = blockIdx.y;
    const int row0 = bm * 128;
    const int col0 = bn * 128;

    const int wm = wave >> 1;
    const int wn = wave & 1;
    const int m_base = wm * 64;
    const int n_base = wn * 64;

    const int lane_lo = lane & 15;
    const int h = lane >> 4;         // 0..3
    const int c0 = 2 * h;            // logical 16B chunk pair for this lane's k-range
    const int c1 = 2 * h + 1;

    f32x4 acc[4][4];
#pragma unroll
    for (int i = 0; i < 4; ++i)
#pragma unroll
        for (int j = 0; j < 4; ++j)
            acc[i][j] = (f32x4){0.f, 0.f, 0.f, 0.f};

    union frag8 { i32x8 v; i32x4 half[2]; };

    for (int k0 = 0; k0 < K; k0 += 128) {
#pragma unroll
        for (int it = 0; it < 4; ++it) {
            int chunk = tid + it * 256;          // 1024 chunks of 16 B per tile
            int r = chunk >> 3;
            int cpos = chunk & 7;
            int csrc = cpos ^ (r & 7);           // source-side permutation
            const unsigned char* gA = Aq + (size_t)(row0 + r) * K + (k0 + csrc * 16);
            const unsigned char* gB = Bq + (size_t)(col0 + r) * K + (k0 + csrc * 16);
            __builtin_amdgcn_global_load_lds(
                (const __attribute__((address_space(1))) void*)gA,
                (__attribute__((address_space(3))) void*)(lA + chunk * 16), 16, 0, 0);
            __builtin_amdgcn_global_load_lds(
                (const __attribute__((address_space(1))) void*)gB,
                (__attribute__((address_space(3))) void*)(lB + chunk * 16), 16, 0, 0);
        }
        __syncthreads();

        frag8 af[4], bf[4];
#pragma unroll
        for (int i = 0; i < 4; ++i) {
            int m = m_base + i * 16 + lane_lo;
            int p0 = c0 ^ (m & 7);
            int p1 = c1 ^ (m & 7);
            af[i].half[0] = *(const i32x4*)(lA + m * 128 + p0 * 16);
            af[i].half[1] = *(const i32x4*)(lA + m * 128 + p1 * 16);
        }
#pragma unroll
        for (int j = 0; j < 4; ++j) {
            int n = n_base + j * 16 + lane_lo;
            int p0 = c0 ^ (n & 7);
            int p1 = c1 ^ (n & 7);
            bf[j].half[0] = *(const i32x4*)(lB + n * 128 + p0 * 16);
            bf[j].half[1] = *(const i32x4*)(lB + n * 128 + p1 * 16);
        }
#pragma unroll
        for (int i = 0; i < 4; ++i)
#pragma unroll
            for (int j = 0; j < 4; ++j)
                acc[i][j] = __builtin_amdgcn_mfma_scale_f32_16x16x128_f8f6f4(
                    af[i].v, bf[j].v, acc[i][j],
                    0, 0,                 // cbsz=fp8, blgp=fp8
                    0, 0x7F7F7F7F,        // A scale opsel, e8m0 1.0
                    0, 0x7F7F7F7F);       // B scale opsel, e8m0 1.0
        __syncthreads();
    }

    // epilogue: out = acc * (1/scale * w_scale) + bias  (fp32 ops match reference)
    float amax = fmaxf(__uint_as_float(*amax_bits), 1e-12f);
    float scale = FP8MAX / amax;
    float a_scale = 1.0f / scale;
    float s = a_scale * w_scale_p[0];

    const int lane_hi = lane >> 4;
#pragma unroll
    for (int i = 0; i < 4; ++i) {
#pragma unroll
        for (int j = 0; j < 4; ++j) {
            int col = col0 + n_base + j * 16 + lane_lo;       // C/D: col = lane&15
            float bv = bias[col];
#pragma unroll
            for (int r = 0; r < 4; ++r) {
                int row = row0 + m_base + i * 16 + lane_hi * 4 + r;  // row = quad*4+reg
                C[(size_t)row * N + col] = acc[i][j][r] * s + bv;
            }
        }
    }
}

// ---------------- launch: 3 kernels total ----------------

extern "C" void kernel_launch(void* const* d_in, const int* in_sizes, int n_in,
                              void* d_out, int out_size, void* d_ws, size_t ws_size,
                              hipStream_t stream) {
    const float* input   = (const float*)d_in[0];   // [M,K] f32
    const float* qweight = (const float*)d_in[1];   // [N,K] f32 (fp8-grid values)
    const float* w_scale = (const float*)d_in[2];   // scalar
    const float* bias    = (const float*)d_in[3];   // [N]
    float* out = (float*)d_out;

    const int N = in_sizes[3];
    const int K = in_sizes[1] / N;
    const int M = in_sizes[0] / K;

    unsigned* amax_bits = (unsigned*)d_ws;
    float* partial = (float*)((char*)d_ws + 256);               // AMAX_BLOCKS floats
    unsigned char* qA = (unsigned char*)d_ws + 16384;
    unsigned char* qW = qA + (size_t)M * K;
    // ws usage: 16384 + M*K + N*K bytes (~37.8 MB)

    const int n4a  = (M / 4) * K;
    const int n16w = (N / 4) * K / 4;
    hipLaunchKernelGGL(amax_and_wquant, dim3(AMAX_BLOCKS + WQ_BLOCKS), dim3(256), 0, stream,
                       (const float4*)input, partial, n4a,
                       (const float4*)qweight, (uint4*)qW, n16w);

    const int n16a = n4a / 4;
    hipLaunchKernelGGL(quant_act, dim3(QA_BLOCKS), dim3(256), 0, stream,
                       (const float4*)input, (uint4*)qA, partial, amax_bits, n16a);

    hipLaunchKernelGGL(gemm_fp8_mx, dim3(N / 128, M / 128), dim3(256), 0, stream,
                       qA, qW, amax_bits, w_scale, bias, out, M, N, K);
}